// Round 9
// baseline (189.244 us; speedup 1.0000x reference)
//
#include <hip/hip_runtime.h>

// MPS layer, round 9: 8-wave k-split chain (2 waves/SIMD -> MFMA/VALU overlap).
//
// Ghost resolved (r8 probe): ~80us first-dispatch-after-idle tax, charged to
// whatever runs first (make_dt). Fixed harness floor; not code-addressable.
//
// Math: M_s = x0*W0[s] + x1*W1[s] = s01*I + x0*D0[s] + x1*D1[s], D = W - I.
// T = (M_0...M_s)^T in MFMA accumulators:
//   T_new = s01*T (exact fp32) + D0^T*(x0*T)_bf16 + D1^T*(x1*T)_bf16.
//
// Layouts (v_mfma_f32_32x32x16_bf16, validated r3-r8, absmax 1.0):
//   A-operand: lane l holds row m=l&31, k = 8*(l>>5)+j (j=0..7)
//   B-operand: lane l holds col n=l&31, k = 8*(l>>5)+j
//   C/D:       lane l holds col  c=l&31, row = (reg&3)+8*(reg>>2)+4*(l>>5)
// acc->B conversion per k-half q: v_permlane32_swap_b32 on reg pairs
// (q*8+r, q*8+4+r); then slot q*8+j = T[...16q+8*hi+j][col].
//
// Round 9 structure: 512 threads/block, 8 waves = (ct, rh):
//   ct = w&3: T col-tile 32ct..32ct+31;  rh = w>>2: T rows 64rh..64rh+63.
// Per step, wave: pp[own mt] = s01*T_own, pp[other] = 0; 4 own k-slices
// (ks = 4rh+ksl) x 4 mt x 2 p = 32 MFMAs -> pp covers ALL 128 rows;
// write other-half pp to exch LDS; bar; stage D[s+1]; read partner pp, add;
// bar. MFMA issue halves per wave; 2 waves/SIMD overlap MFMA with VALU/LDS.
//
// ws: res[2][128][128][128] f32 (16MB) | Dt (4MB bf16 fragment-major)
// Dt[mat][(ks*4+mt)*512 + l*8 + j] = W[mat][16ks+8(l>>5)+j][32mt+(l&31)] - I

typedef __attribute__((ext_vector_type(8))) short short8v;
typedef __attribute__((ext_vector_type(16))) float f32x16;

__device__ __forceinline__ unsigned cvt_pk_bf16(float lo, float hi) {
  unsigned r;
  asm("v_cvt_pk_bf16_f32 %0, %1, %2" : "=v"(r) : "v"(lo), "v"(hi));
  return r;
}

#define GLOAD_LDS16(g, l)                                          \
  __builtin_amdgcn_global_load_lds(                                \
      (const __attribute__((address_space(1))) void*)(g),          \
      (__attribute__((address_space(3))) void*)(l), 16, 0, 0)

// 256 blocks: block = (matrix, row-half). Stage 64x128 f32 to LDS (coalesced),
// gather A-fragments (conflict-free scalar reads), write coalesced 16B.
__global__ __launch_bounds__(256) void make_dt(const float* __restrict__ left,
                                               const float* __restrict__ right,
                                               ushort* __restrict__ Dt) {
  __shared__ float lw[64 * 132];
  const int tid = threadIdx.x;
  const int mat = blockIdx.x >> 1;   // side*64 + p*32 + s
  const int rh  = blockIdx.x & 1;    // rows 64*rh .. 64*rh+63
  const float* W = (mat >= 64 ? right : left) + (size_t)(mat & 63) * 16384 +
                   (size_t)rh * 8192;

#pragma unroll
  for (int it = 0; it < 8; ++it) {
    int g = it * 256 + tid;
    float4 v = *(const float4*)(W + g * 4);
    *(float4*)&lw[(g >> 5) * 132 + (g & 31) * 4] = v;
  }
  __syncthreads();

#pragma unroll
  for (int ff = 0; ff < 4; ++ff) {
    int f = ff * 256 + tid;             // frag slot within this half: 0..1023
    int l = f & 63, mt = (f >> 6) & 3, ksl = f >> 8;
    int m = 32 * mt + (l & 31);
    int kbl = 16 * ksl + 8 * (l >> 5);
    float v[8];
#pragma unroll
    for (int j = 0; j < 8; ++j)
      v[j] = lw[(kbl + j) * 132 + m] - ((64 * rh + kbl + j == m) ? 1.0f : 0.0f);
    uint4 o;
    o.x = cvt_pk_bf16(v[0], v[1]);
    o.y = cvt_pk_bf16(v[2], v[3]);
    o.z = cvt_pk_bf16(v[4], v[5]);
    o.w = cvt_pk_bf16(v[6], v[7]);
    *(uint4*)(Dt + (size_t)mat * 16384 +
              (size_t)(((4 * rh + ksl) * 4 + mt) * 64 + l) * 8) = o;
  }
}

// Stage both D mats of site s into the single LDS D buffer (64 KB), 8
// gload_lds x16B per wave, thread-linear layout (matches Dt exactly).
__device__ __forceinline__ void stage_D(const ushort* __restrict__ DtH, int s,
                                        ushort* ldsD, int tid, int w) {
#pragma unroll
  for (int i = 0; i < 8; ++i) {
    const int p = i >> 2;
    const ushort* g =
        DtH + (size_t)(p * 32 + s) * 16384 + (i & 3) * 4096 + tid * 8;
    GLOAD_LDS16(g, ldsD + i * 4096 + w * 512);
  }
}

__global__ __launch_bounds__(512, 1) void mps_chain_mfma(
    const float* __restrict__ inp, const float* __restrict__ left,
    const float* __restrict__ right, const ushort* __restrict__ Dt,
    float* __restrict__ res) {
  __shared__ __align__(16) ushort ldsD[32768];  // 64 KB: p*16384 + (ks*4+mt)*512 + lane*8
  __shared__ __align__(16) float exch[16384];   // 64 KB: w*2048 + r*256 + lane*4
  __shared__ float xs[64];

  const int tid  = threadIdx.x;
  const int half = blockIdx.x >> 7;
  const int b    = blockIdx.x & 127;
  const int lane = tid & 63;
  const int w    = tid >> 6;   // 0..7
  const int ct   = w & 3;      // col-tile
  const int rh   = w >> 2;     // row-half (k-slices 4rh..4rh+3, T rows 64rh..)
  const int hi   = lane >> 5;
  const int cg   = 32 * ct + (lane & 31);

  if (tid < 64) xs[tid] = inp[b * 128 + half * 64 + tid];

  const ushort* DtH = Dt + (size_t)(half * 2) * 32 * 16384;

  stage_D(DtH, 1, ldsD, tid, w);  // latency hides under T0 init + barrier

  __syncthreads();  // xs visible; D[1] drained (vmcnt0 before barrier)

  // T_0 own half: accL[tl] = T rows 64rh+32tl..+31, col cg.
  // T0[row][cg] = M0[cg][row]
  f32x16 accL[2];
  {
    const float* Wg = half ? right : left;
    const float x0 = xs[0], x1 = xs[1];
#pragma unroll
    for (int tl = 0; tl < 2; ++tl)
#pragma unroll
      for (int g = 0; g < 4; ++g) {
        const int row = 64 * rh + 32 * tl + 8 * g + 4 * hi;
        const float4 w0 = *(const float4*)(Wg + cg * 128 + row);
        const float4 w1 = *(const float4*)(Wg + 32 * 16384 + cg * 128 + row);
        accL[tl][4 * g + 0] = x0 * w0.x + x1 * w1.x;
        accL[tl][4 * g + 1] = x0 * w0.y + x1 * w1.y;
        accL[tl][4 * g + 2] = x0 * w0.z + x1 * w1.z;
        accL[tl][4 * g + 3] = x0 * w0.w + x1 * w1.w;
      }
  }

#pragma unroll 1
  for (int s = 1; s < 32; ++s) {
    const float x0 = xs[2 * s], x1 = xs[2 * s + 1];
    const float s01 = x0 + x1;

    // pp[mt]: full-height partial, col cg. Own half starts at s01*T, other 0.
    f32x16 pp[4];
    if (rh == 0) {
#pragma unroll
      for (int r = 0; r < 16; ++r) {
        pp[0][r] = s01 * accL[0][r];
        pp[1][r] = s01 * accL[1][r];
        pp[2][r] = 0.f;
        pp[3][r] = 0.f;
      }
    } else {
#pragma unroll
      for (int r = 0; r < 16; ++r) {
        pp[0][r] = 0.f;
        pp[1][r] = 0.f;
        pp[2][r] = s01 * accL[0][r];
        pp[3][r] = s01 * accL[1][r];
      }
    }

    // own 4 k-slices: permute accL in place, build scaled y, 8 MFMAs each
#pragma unroll
    for (int ksl = 0; ksl < 4; ++ksl) {
      const int tl = ksl >> 1, q = ksl & 1;
#pragma unroll
      for (int r = 0; r < 4; ++r) {
        float a  = accL[tl][q * 8 + r];
        float b2 = accL[tl][q * 8 + 4 + r];
        asm volatile("v_permlane32_swap_b32 %0, %1" : "+v"(a), "+v"(b2));
        accL[tl][q * 8 + r]     = a;   // T[64rh+32tl+16q+8hi+r][cg]
        accL[tl][q * 8 + 4 + r] = b2;
      }
      uint4 p0, p1;
      {
        const float* v = (const float*)&accL[tl] + q * 8;
        p0.x = cvt_pk_bf16(x0 * v[0], x0 * v[1]);
        p0.y = cvt_pk_bf16(x0 * v[2], x0 * v[3]);
        p0.z = cvt_pk_bf16(x0 * v[4], x0 * v[5]);
        p0.w = cvt_pk_bf16(x0 * v[6], x0 * v[7]);
        p1.x = cvt_pk_bf16(x1 * v[0], x1 * v[1]);
        p1.y = cvt_pk_bf16(x1 * v[2], x1 * v[3]);
        p1.z = cvt_pk_bf16(x1 * v[4], x1 * v[5]);
        p1.w = cvt_pk_bf16(x1 * v[6], x1 * v[7]);
      }
      const short8v y0 = __builtin_bit_cast(short8v, p0);
      const short8v y1 = __builtin_bit_cast(short8v, p1);
      const int ks = 4 * rh + ksl;
#pragma unroll
      for (int mt = 0; mt < 4; ++mt) {
        short8v d0 = *(const short8v*)&ldsD[(ks * 4 + mt) * 512 + lane * 8];
        short8v d1 = *(const short8v*)&ldsD[16384 + (ks * 4 + mt) * 512 + lane * 8];
        pp[mt] = __builtin_amdgcn_mfma_f32_32x32x16_bf16(d0, y0, pp[mt], 0, 0, 0);
        pp[mt] = __builtin_amdgcn_mfma_f32_32x32x16_bf16(d1, y1, pp[mt], 0, 0, 0);
      }
    }

    // write other-half partials to exch (conflict-free: lanes stride 16B)
    {
      float* wb = exch + w * 2048 + lane * 4;
      if (rh == 0) {
#pragma unroll
        for (int tl2 = 0; tl2 < 2; ++tl2)
#pragma unroll
          for (int g = 0; g < 4; ++g) {
            float4 val = {pp[2 + tl2][4 * g + 0], pp[2 + tl2][4 * g + 1],
                          pp[2 + tl2][4 * g + 2], pp[2 + tl2][4 * g + 3]};
            *(float4*)(wb + (tl2 * 4 + g) * 256) = val;
          }
      } else {
#pragma unroll
        for (int tl2 = 0; tl2 < 2; ++tl2)
#pragma unroll
          for (int g = 0; g < 4; ++g) {
            float4 val = {pp[tl2][4 * g + 0], pp[tl2][4 * g + 1],
                          pp[tl2][4 * g + 2], pp[tl2][4 * g + 3]};
            *(float4*)(wb + (tl2 * 4 + g) * 256) = val;
          }
      }
    }
    __syncthreads();  // exch visible; all D[s] reads done (lgkm drained)

    if (s < 31) stage_D(DtH, s + 1, ldsD, tid, w);  // safe: reads complete

    // read partner's partials for our rows, add -> new accL
    {
      const float* rb = exch + (w ^ 4) * 2048 + lane * 4;
      if (rh == 0) {
#pragma unroll
        for (int tl2 = 0; tl2 < 2; ++tl2)
#pragma unroll
          for (int g = 0; g < 4; ++g) {
            float4 e = *(const float4*)(rb + (tl2 * 4 + g) * 256);
            accL[tl2][4 * g + 0] = pp[tl2][4 * g + 0] + e.x;
            accL[tl2][4 * g + 1] = pp[tl2][4 * g + 1] + e.y;
            accL[tl2][4 * g + 2] = pp[tl2][4 * g + 2] + e.z;
            accL[tl2][4 * g + 3] = pp[tl2][4 * g + 3] + e.w;
          }
      } else {
#pragma unroll
        for (int tl2 = 0; tl2 < 2; ++tl2)
#pragma unroll
          for (int g = 0; g < 4; ++g) {
            float4 e = *(const float4*)(rb + (tl2 * 4 + g) * 256);
            accL[tl2][4 * g + 0] = pp[2 + tl2][4 * g + 0] + e.x;
            accL[tl2][4 * g + 1] = pp[2 + tl2][4 * g + 1] + e.y;
            accL[tl2][4 * g + 2] = pp[2 + tl2][4 * g + 2] + e.z;
            accL[tl2][4 * g + 3] = pp[2 + tl2][4 * g + 3] + e.w;
          }
      }
    }
    __syncthreads();  // exch reads done; next step may overwrite; D[s+1] drained
  }

  // T[r][cg] = L[cg][r]: wave stores its own 64 rows x 32 cols
  float* O = res + (size_t)(half * 128 + b) * 16384;
#pragma unroll
  for (int tl = 0; tl < 2; ++tl)
#pragma unroll
    for (int g = 0; g < 4; ++g) {
      const int row = 64 * rh + 32 * tl + 8 * g + 4 * hi;
      float4 o = {accL[tl][4 * g + 0], accL[tl][4 * g + 1],
                  accL[tl][4 * g + 2], accL[tl][4 * g + 3]};
      *(float4*)(O + cg * 128 + row) = o;
    }
}

#define TS 132  // padded LDS stride for the fp32 final kernel

__global__ __launch_bounds__(256) void mps_final(const float* __restrict__ res,
                                                 const float* __restrict__ middle,
                                                 float* __restrict__ out) {
  __shared__ float lA[128 * TS];  // R = res[1][b]
  __shared__ float lB[128 * TS];  // L = res[0][b]
  __shared__ float red[4][10];

  const int tid = threadIdx.x;
  const int b   = blockIdx.x;
  const float* Rg = res + (size_t)(128 + b) * 16384;
  const float* Lg = res + (size_t)b * 16384;

#pragma unroll
  for (int it = 0; it < 16; ++it) {
    int g = it * 256 + tid;
    int row = g >> 5, col = (g & 31) * 4;
    *(float4*)&lA[row * TS + col] = *(const float4*)(Rg + g * 4);
    *(float4*)&lB[row * TS + col] = *(const float4*)(Lg + g * 4);
  }
  __syncthreads();

  const int ty = tid >> 4, tx = tid & 15;
  const int k0 = ty * 8, j0 = tx * 8;

  float ct[8][8];
#pragma unroll
  for (int i = 0; i < 8; ++i)
#pragma unroll
    for (int j = 0; j < 8; ++j) ct[i][j] = 0.f;

  for (int k = 0; k < 128; k += 4) {
    float4 a[8];
#pragma unroll
    for (int i = 0; i < 8; ++i)
      a[i] = *(const float4*)&lA[(k0 + i) * TS + k];
    float4 b0[4], b1[4];
#pragma unroll
    for (int kk = 0; kk < 4; ++kk) {
      b0[kk] = *(const float4*)&lB[(k + kk) * TS + j0];
      b1[kk] = *(const float4*)&lB[(k + kk) * TS + j0 + 4];
    }
#pragma unroll
    for (int i = 0; i < 8; ++i) {
      const float av[4] = {a[i].x, a[i].y, a[i].z, a[i].w};
#pragma unroll
      for (int kk = 0; kk < 4; ++kk) {
        const float aa = av[kk];
        ct[i][0] = fmaf(aa, b0[kk].x, ct[i][0]);
        ct[i][1] = fmaf(aa, b0[kk].y, ct[i][1]);
        ct[i][2] = fmaf(aa, b0[kk].z, ct[i][2]);
        ct[i][3] = fmaf(aa, b0[kk].w, ct[i][3]);
        ct[i][4] = fmaf(aa, b1[kk].x, ct[i][4]);
        ct[i][5] = fmaf(aa, b1[kk].y, ct[i][5]);
        ct[i][6] = fmaf(aa, b1[kk].z, ct[i][6]);
        ct[i][7] = fmaf(aa, b1[kk].w, ct[i][7]);
      }
    }
  }
  // ct[i][jj] = (R@L)[k0+i][j0+jj];  out[b,c] = sum mid[c][j][k] * P[k][j]
#pragma unroll
  for (int cc = 0; cc < 10; ++cc) {
    const float* m = middle + cc * 16384;
    float accv = 0.f;
#pragma unroll
    for (int jj = 0; jj < 8; ++jj) {
      const float* mr = m + (j0 + jj) * 128 + k0;
      float4 m0 = *(const float4*)(mr);
      float4 m1 = *(const float4*)(mr + 4);
      accv += m0.x * ct[0][jj] + m0.y * ct[1][jj] + m0.z * ct[2][jj] + m0.w * ct[3][jj];
      accv += m1.x * ct[4][jj] + m1.y * ct[5][jj] + m1.z * ct[6][jj] + m1.w * ct[7][jj];
    }
    float v = accv;
#pragma unroll
    for (int off = 32; off > 0; off >>= 1) v += __shfl_down(v, off);
    if ((tid & 63) == 0) red[tid >> 6][cc] = v;
  }
  __syncthreads();
  if (tid < 10)
    out[b * 10 + tid] = red[0][tid] + red[1][tid] + red[2][tid] + red[3][tid];
}

extern "C" void kernel_launch(void* const* d_in, const int* in_sizes, int n_in,
                              void* d_out, int out_size, void* d_ws, size_t ws_size,
                              hipStream_t stream) {
  const float* inputs = (const float*)d_in[0];  // (128, 64, 2)
  const float* left   = (const float*)d_in[1];  // (2, 32, 128, 128)
  const float* right  = (const float*)d_in[2];  // (2, 32, 128, 128)
  const float* middle = (const float*)d_in[3];  // (10, 128, 128)
  float* out = (float*)d_out;                   // (128, 10)

  float*  res = (float*)d_ws;                                       // 16 MB
  ushort* Dt  = (ushort*)((char*)d_ws + (size_t)16 * 1024 * 1024);  // 4 MB

  make_dt<<<256, 256, 0, stream>>>(left, right, Dt);
  mps_chain_mfma<<<256, 512, 0, stream>>>(inputs, left, right, Dt, res);
  mps_final<<<128, 256, 0, stream>>>(res, middle, out);
}

// Round 10
// 183.700 us; speedup vs baseline: 1.0302x; 1.0302x over previous
//
#include <hip/hip_runtime.h>

// MPS layer, round 10: single-matmul chain via per-step E = x0*D0 + x1*D1.
//
// Math: M_s = x0*W0[s] + x1*W1[s] = s01*I + E_s,  E_s = x0*D0[s] + x1*D1[s].
// T = (M_0...M_s)^T in MFMA accumulators:
//   T_new = s01*T (exact fp32 VALU) + E_s^T * (T)_bf16   -- ONE matmul/step.
// E_s is chain-specific but SHARED by the block's 4 waves: built cooperatively
// once per step (elementwise on Dt's fragment-major layout -> no re-indexing),
// double-buffered in LDS (2 x 32 KB). Halves the MFMA floor vs r4 (32 vs 64
// MFMA/wave/step) and removes per-slice x-scaling from the y-conversion.
//
// Layouts (v_mfma_f32_32x32x16_bf16, validated r3-r9, absmax 1.0):
//   A-operand: lane l holds row m=l&31, k = 8*(l>>5)+j (j=0..7)
//   B-operand: lane l holds col n=l&31, k = 8*(l>>5)+j
//   C/D:       lane l holds col  c=l&31, row = (reg&3)+8*(reg>>2)+4*(l>>5)
// acc->B conversion per k-half q: v_permlane32_swap_b32 on reg pairs
// (q*8+r, q*8+4+r); then slot q*8+j = T[32t+16q+8*hi+j][col].
//
// Ghost (r8 probe): ~80us first-dispatch-after-idle tax lands on make_dt;
// harness floor, not code-addressable.
//
// ws: res[2][128][128][128] f32 (16MB) | Dt (4MB bf16 fragment-major)
// Dt[mat][(ks*4+mt)*512 + l*8 + j] = W[mat][16ks+8(l>>5)+j][32mt+(l&31)] - I

typedef __attribute__((ext_vector_type(8))) short short8v;
typedef __attribute__((ext_vector_type(16))) float f32x16;

__device__ __forceinline__ unsigned cvt_pk_bf16(float lo, float hi) {
  unsigned r;
  asm("v_cvt_pk_bf16_f32 %0, %1, %2" : "=v"(r) : "v"(lo), "v"(hi));
  return r;
}

// elementwise bf16-pair combine: out = bf16(x0*a + x1*b) per 16-bit lane
__device__ __forceinline__ unsigned combine_u(unsigned a, unsigned b, float x0,
                                              float x1) {
  float al = __builtin_bit_cast(float, a << 16);
  float ah = __builtin_bit_cast(float, a & 0xffff0000u);
  float bl = __builtin_bit_cast(float, b << 16);
  float bh = __builtin_bit_cast(float, b & 0xffff0000u);
  return cvt_pk_bf16(fmaf(x0, al, x1 * bl), fmaf(x0, ah, x1 * bh));
}

__device__ __forceinline__ uint4 combine4(uint4 a, uint4 b, float x0, float x1) {
  uint4 o;
  o.x = combine_u(a.x, b.x, x0, x1);
  o.y = combine_u(a.y, b.y, x0, x1);
  o.z = combine_u(a.z, b.z, x0, x1);
  o.w = combine_u(a.w, b.w, x0, x1);
  return o;
}

// 256 blocks: block = (matrix, row-half). Stage 64x128 f32 to LDS (coalesced),
// gather A-fragments (conflict-free scalar reads), write coalesced 16B.
__global__ __launch_bounds__(256) void make_dt(const float* __restrict__ left,
                                               const float* __restrict__ right,
                                               ushort* __restrict__ Dt) {
  __shared__ float lw[64 * 132];
  const int tid = threadIdx.x;
  const int mat = blockIdx.x >> 1;   // side*64 + p*32 + s
  const int rh  = blockIdx.x & 1;    // rows 64*rh .. 64*rh+63
  const float* W = (mat >= 64 ? right : left) + (size_t)(mat & 63) * 16384 +
                   (size_t)rh * 8192;

#pragma unroll
  for (int it = 0; it < 8; ++it) {
    int g = it * 256 + tid;
    float4 v = *(const float4*)(W + g * 4);
    *(float4*)&lw[(g >> 5) * 132 + (g & 31) * 4] = v;
  }
  __syncthreads();

#pragma unroll
  for (int ff = 0; ff < 4; ++ff) {
    int f = ff * 256 + tid;             // frag slot within this half: 0..1023
    int l = f & 63, mt = (f >> 6) & 3, ksl = f >> 8;
    int m = 32 * mt + (l & 31);
    int kbl = 16 * ksl + 8 * (l >> 5);
    float v[8];
#pragma unroll
    for (int j = 0; j < 8; ++j)
      v[j] = lw[(kbl + j) * 132 + m] - ((64 * rh + kbl + j == m) ? 1.0f : 0.0f);
    uint4 o;
    o.x = cvt_pk_bf16(v[0], v[1]);
    o.y = cvt_pk_bf16(v[2], v[3]);
    o.z = cvt_pk_bf16(v[4], v[5]);
    o.w = cvt_pk_bf16(v[6], v[7]);
    *(uint4*)(Dt + (size_t)mat * 16384 +
              (size_t)(((4 * rh + ksl) * 4 + mt) * 64 + l) * 8) = o;
  }
}

__global__ __launch_bounds__(256, 1) void mps_chain_mfma(
    const float* __restrict__ inp, const float* __restrict__ left,
    const float* __restrict__ right, const ushort* __restrict__ Dt,
    float* __restrict__ res) {
  __shared__ __align__(16) ushort ldsE[2][16384];  // E frag-major, 2x32KB
  __shared__ float xs[64];

  const int tid  = threadIdx.x;
  const int half = blockIdx.x >> 7;
  const int b    = blockIdx.x & 127;
  const int lane = tid & 63;
  const int w    = tid >> 6;  // wave owns T cols 32w..32w+31
  const int hi   = lane >> 5;
  const int cg   = 32 * w + (lane & 31);

  if (tid < 64) xs[tid] = inp[b * 128 + half * 64 + tid];

  const ushort* D0 = Dt + (size_t)(half * 2) * 32 * 16384;      // D0 slab
  const ushort* D1 = D0 + (size_t)32 * 16384;                   // D1 slab

  __syncthreads();  // xs ready

  f32x16 acc[4];  // T: acc[t] = rows 32t..32t+31, col cg

  // T_0 = M_0^T from W (fp32): T0[row][cg] = M0[cg][row]
  {
    const float* Wg = half ? right : left;
    const float x0 = xs[0], x1 = xs[1];
#pragma unroll
    for (int t = 0; t < 4; ++t)
#pragma unroll
      for (int g = 0; g < 4; ++g) {
        const int row = 32 * t + 8 * g + 4 * hi;
        const float4 w0 = *(const float4*)(Wg + cg * 128 + row);
        const float4 w1 = *(const float4*)(Wg + 32 * 16384 + cg * 128 + row);
        acc[t][4 * g + 0] = x0 * w0.x + x1 * w1.x;
        acc[t][4 * g + 1] = x0 * w0.y + x1 * w1.y;
        acc[t][4 * g + 2] = x0 * w0.z + x1 * w1.z;
        acc[t][4 * g + 3] = x0 * w0.w + x1 * w1.w;
      }
  }

  // prologue: build E[1] into buf0 (elementwise on frag-major slots)
  {
    const float x0 = xs[2], x1 = xs[3];
    const ushort* g0 = D0 + 16384;  // s=1
    const ushort* g1 = D1 + 16384;
#pragma unroll
    for (int i = 0; i < 8; ++i) {
      const int slot = i * 256 + tid;
      uint4 a = *(const uint4*)(g0 + slot * 8);
      uint4 bb = *(const uint4*)(g1 + slot * 8);
      *(uint4*)&ldsE[0][slot * 8] = combine4(a, bb, x0, x1);
    }
  }
  __syncthreads();  // E[1] visible

  int cur = 0;
#pragma unroll 1
  for (int s = 1; s < 32; ++s) {
    const float x0 = xs[2 * s], x1 = xs[2 * s + 1];
    const float s01 = x0 + x1;
    const ushort* bufC = ldsE[cur];

    // issue next step's Dt loads early (held in regs across MFMA phase)
    uint4 ga[8], gb[8];
    if (s < 31) {
      const ushort* g0 = D0 + (size_t)(s + 1) * 16384;
      const ushort* g1 = D1 + (size_t)(s + 1) * 16384;
#pragma unroll
      for (int i = 0; i < 8; ++i) {
        const int slot = i * 256 + tid;
        ga[i] = *(const uint4*)(g0 + slot * 8);
        gb[i] = *(const uint4*)(g1 + slot * 8);
      }
    }

    // identity part (exact fp32) before acc is permuted in-place
    f32x16 tn[4];
#pragma unroll
    for (int t = 0; t < 4; ++t)
#pragma unroll
      for (int r = 0; r < 16; ++r) tn[t][r] = s01 * acc[t][r];

    // per k-slice: convert T -> bf16 B-frag (unscaled), then 4 MFMAs
#pragma unroll
    for (int ks = 0; ks < 8; ++ks) {
      const int t = ks >> 1, q = ks & 1;
#pragma unroll
      for (int r = 0; r < 4; ++r) {
        float a  = acc[t][q * 8 + r];
        float b2 = acc[t][q * 8 + 4 + r];
        asm volatile("v_permlane32_swap_b32 %0, %1" : "+v"(a), "+v"(b2));
        acc[t][q * 8 + r]     = a;   // T[32t+16q+8hi+r][cg]
        acc[t][q * 8 + 4 + r] = b2;  // T[32t+16q+8hi+4+r][cg]
      }
      uint4 py;
      {
        const float* v = (const float*)&acc[t] + q * 8;
        py.x = cvt_pk_bf16(v[0], v[1]);
        py.y = cvt_pk_bf16(v[2], v[3]);
        py.z = cvt_pk_bf16(v[4], v[5]);
        py.w = cvt_pk_bf16(v[6], v[7]);
      }
      const short8v y = __builtin_bit_cast(short8v, py);
#pragma unroll
      for (int mt = 0; mt < 4; ++mt) {
        short8v e = *(const short8v*)&bufC[(ks * 4 + mt) * 512 + lane * 8];
        tn[mt] = __builtin_amdgcn_mfma_f32_32x32x16_bf16(e, y, tn[mt], 0, 0, 0);
      }
    }

    // build E[s+1] into the other buffer (independent of this step's MFMAs)
    if (s < 31) {
      const float xn0 = xs[2 * s + 2], xn1 = xs[2 * s + 3];
      ushort* bufN = ldsE[cur ^ 1];
#pragma unroll
      for (int i = 0; i < 8; ++i) {
        const int slot = i * 256 + tid;
        *(uint4*)&bufN[slot * 8] = combine4(ga[i], gb[i], xn0, xn1);
      }
    }

#pragma unroll
    for (int t = 0; t < 4; ++t) acc[t] = tn[t];
    __syncthreads();  // E[s] reads done by all; E[s+1] writes visible
    cur ^= 1;
  }

  // T[r][cg] = L[cg][r]: store row cg row-major
  float* O = res + (size_t)(half * 128 + b) * 16384;
#pragma unroll
  for (int t = 0; t < 4; ++t)
#pragma unroll
    for (int g = 0; g < 4; ++g) {
      const int row = 32 * t + 8 * g + 4 * hi;
      float4 o = {acc[t][4 * g + 0], acc[t][4 * g + 1], acc[t][4 * g + 2],
                  acc[t][4 * g + 3]};
      *(float4*)(O + cg * 128 + row) = o;
    }
}

#define TS 132  // padded LDS stride for the fp32 final kernel

__global__ __launch_bounds__(256) void mps_final(const float* __restrict__ res,
                                                 const float* __restrict__ middle,
                                                 float* __restrict__ out) {
  __shared__ float lA[128 * TS];  // R = res[1][b]
  __shared__ float lB[128 * TS];  // L = res[0][b]
  __shared__ float red[4][10];

  const int tid = threadIdx.x;
  const int b   = blockIdx.x;
  const float* Rg = res + (size_t)(128 + b) * 16384;
  const float* Lg = res + (size_t)b * 16384;

#pragma unroll
  for (int it = 0; it < 16; ++it) {
    int g = it * 256 + tid;
    int row = g >> 5, col = (g & 31) * 4;
    *(float4*)&lA[row * TS + col] = *(const float4*)(Rg + g * 4);
    *(float4*)&lB[row * TS + col] = *(const float4*)(Lg + g * 4);
  }
  __syncthreads();

  const int ty = tid >> 4, tx = tid & 15;
  const int k0 = ty * 8, j0 = tx * 8;

  float ct[8][8];
#pragma unroll
  for (int i = 0; i < 8; ++i)
#pragma unroll
    for (int j = 0; j < 8; ++j) ct[i][j] = 0.f;

  for (int k = 0; k < 128; k += 4) {
    float4 a[8];
#pragma unroll
    for (int i = 0; i < 8; ++i)
      a[i] = *(const float4*)&lA[(k0 + i) * TS + k];
    float4 b0[4], b1[4];
#pragma unroll
    for (int kk = 0; kk < 4; ++kk) {
      b0[kk] = *(const float4*)&lB[(k + kk) * TS + j0];
      b1[kk] = *(const float4*)&lB[(k + kk) * TS + j0 + 4];
    }
#pragma unroll
    for (int i = 0; i < 8; ++i) {
      const float av[4] = {a[i].x, a[i].y, a[i].z, a[i].w};
#pragma unroll
      for (int kk = 0; kk < 4; ++kk) {
        const float aa = av[kk];
        ct[i][0] = fmaf(aa, b0[kk].x, ct[i][0]);
        ct[i][1] = fmaf(aa, b0[kk].y, ct[i][1]);
        ct[i][2] = fmaf(aa, b0[kk].z, ct[i][2]);
        ct[i][3] = fmaf(aa, b0[kk].w, ct[i][3]);
        ct[i][4] = fmaf(aa, b1[kk].x, ct[i][4]);
        ct[i][5] = fmaf(aa, b1[kk].y, ct[i][5]);
        ct[i][6] = fmaf(aa, b1[kk].z, ct[i][6]);
        ct[i][7] = fmaf(aa, b1[kk].w, ct[i][7]);
      }
    }
  }
  // ct[i][jj] = (R@L)[k0+i][j0+jj];  out[b,c] = sum mid[c][j][k] * P[k][j]
#pragma unroll
  for (int cc = 0; cc < 10; ++cc) {
    const float* m = middle + cc * 16384;
    float accv = 0.f;
#pragma unroll
    for (int jj = 0; jj < 8; ++jj) {
      const float* mr = m + (j0 + jj) * 128 + k0;
      float4 m0 = *(const float4*)(mr);
      float4 m1 = *(const float4*)(mr + 4);
      accv += m0.x * ct[0][jj] + m0.y * ct[1][jj] + m0.z * ct[2][jj] + m0.w * ct[3][jj];
      accv += m1.x * ct[4][jj] + m1.y * ct[5][jj] + m1.z * ct[6][jj] + m1.w * ct[7][jj];
    }
    float v = accv;
#pragma unroll
    for (int off = 32; off > 0; off >>= 1) v += __shfl_down(v, off);
    if ((tid & 63) == 0) red[tid >> 6][cc] = v;
  }
  __syncthreads();
  if (tid < 10)
    out[b * 10 + tid] = red[0][tid] + red[1][tid] + red[2][tid] + red[3][tid];
}

extern "C" void kernel_launch(void* const* d_in, const int* in_sizes, int n_in,
                              void* d_out, int out_size, void* d_ws, size_t ws_size,
                              hipStream_t stream) {
  const float* inputs = (const float*)d_in[0];  // (128, 64, 2)
  const float* left   = (const float*)d_in[1];  // (2, 32, 128, 128)
  const float* right  = (const float*)d_in[2];  // (2, 32, 128, 128)
  const float* middle = (const float*)d_in[3];  // (10, 128, 128)
  float* out = (float*)d_out;                   // (128, 10)

  float*  res = (float*)d_ws;                                       // 16 MB
  ushort* Dt  = (ushort*)((char*)d_ws + (size_t)16 * 1024 * 1024);  // 4 MB

  make_dt<<<256, 256, 0, stream>>>(left, right, Dt);
  mps_chain_mfma<<<256, 256, 0, stream>>>(inputs, left, right, Dt, res);
  mps_final<<<128, 256, 0, stream>>>(res, middle, out);
}